// Round 1
// 1057.552 us; speedup vs baseline: 1.0865x; 1.0865x over previous
//
#include <hip/hip_runtime.h>

// ---------- problem dims ----------
constexpr int BN = 32;      // batch
constexpr int DM = 512;     // d_model = d_inner
constexpr int SD = 64;      // state dim S
constexpr int LL = 4096;    // L = 64*64
constexpr int C3 = 192;     // 3*S

// 16 FMAs of the 4x4 outer product
#define OUTER16(acc, a4, b4)                                               \
    acc[0][0] += a4.x * b4.x; acc[0][1] += a4.x * b4.y;                    \
    acc[0][2] += a4.x * b4.z; acc[0][3] += a4.x * b4.w;                    \
    acc[1][0] += a4.y * b4.x; acc[1][1] += a4.y * b4.y;                    \
    acc[1][2] += a4.y * b4.z; acc[1][3] += a4.y * b4.w;                    \
    acc[2][0] += a4.z * b4.x; acc[2][1] += a4.z * b4.y;                    \
    acc[2][2] += a4.z * b4.z; acc[2][3] += a4.z * b4.w;                    \
    acc[3][0] += a4.w * b4.x; acc[3][1] += a4.w * b4.y;                    \
    acc[3][2] += a4.w * b4.z; acc[3][3] += a4.w * b4.w;

// ---------- K1: bcdt[b,o,l] = sum_c w[o,c]*x[b,c,l] + bias[o]  (M=192,N=4096,K=512) ----------
// v2: 64x128 tile, BK=32, register prefetch, padded wl (2-way max conflicts)
__global__ __launch_bounds__(256) void k1_bcdt(const float* __restrict__ x,
                                               const float* __restrict__ w,
                                               const float* __restrict__ bias,
                                               float* __restrict__ out) {
    int b = blockIdx.z, o0 = blockIdx.y * 64, l0 = blockIdx.x * 128;
    __shared__ float wl[32][68];    // [k][o], padded: stride 68 -> 2-way max
    __shared__ float xl[32][128];   // [k][l], rows written lane-contiguous
    int t = threadIdx.x;
    int tx = t & 15, ty = t >> 4;
    float acc0[4][4] = {}, acc1[4][4] = {};
    const float* xb = x + (size_t)b * DM * LL;
    int oi = t >> 2, kkw = (t & 3) * 4;
    int ci = t >> 5, li = (t & 31) * 4;
    // prefetch k0 = 0
    float4 wv0 = *(const float4*)&w[(size_t)(o0 + oi) * DM + kkw];
    float4 wv1 = *(const float4*)&w[(size_t)(o0 + oi) * DM + kkw + 16];
    float4 xv0 = *(const float4*)&xb[(size_t)(ci +  0) * LL + l0 + li];
    float4 xv1 = *(const float4*)&xb[(size_t)(ci +  8) * LL + l0 + li];
    float4 xv2 = *(const float4*)&xb[(size_t)(ci + 16) * LL + l0 + li];
    float4 xv3 = *(const float4*)&xb[(size_t)(ci + 24) * LL + l0 + li];
    for (int k0 = 0; k0 < DM; k0 += 32) {
        wl[kkw +  0][oi] = wv0.x; wl[kkw +  1][oi] = wv0.y;
        wl[kkw +  2][oi] = wv0.z; wl[kkw +  3][oi] = wv0.w;
        wl[kkw + 16][oi] = wv1.x; wl[kkw + 17][oi] = wv1.y;
        wl[kkw + 18][oi] = wv1.z; wl[kkw + 19][oi] = wv1.w;
        *(float4*)&xl[ci +  0][li] = xv0;
        *(float4*)&xl[ci +  8][li] = xv1;
        *(float4*)&xl[ci + 16][li] = xv2;
        *(float4*)&xl[ci + 24][li] = xv3;
        __syncthreads();
        if (k0 + 32 < DM) {   // issue next-slab loads; latency hides under FMAs
            const float* wp = &w[(size_t)(o0 + oi) * DM + k0 + 32 + kkw];
            wv0 = *(const float4*)wp;
            wv1 = *(const float4*)(wp + 16);
            const float* xp = &xb[(size_t)(k0 + 32 + ci) * LL + l0 + li];
            xv0 = *(const float4*)xp;
            xv1 = *(const float4*)(xp + (size_t)8 * LL);
            xv2 = *(const float4*)(xp + (size_t)16 * LL);
            xv3 = *(const float4*)(xp + (size_t)24 * LL);
        }
#pragma unroll
        for (int kk = 0; kk < 32; ++kk) {
            float4 a4 = *(const float4*)&wl[kk][ty * 4];
            float4 b4 = *(const float4*)&xl[kk][tx * 4];
            float4 c4 = *(const float4*)&xl[kk][64 + tx * 4];
            OUTER16(acc0, a4, b4)
            OUTER16(acc1, a4, c4)
        }
        __syncthreads();
    }
#pragma unroll
    for (int r = 0; r < 4; ++r) {
        float bo = bias[o0 + ty * 4 + r];
        float* op = &out[((size_t)b * C3 + o0 + ty * 4 + r) * LL + l0];
        *(float4*)&op[tx * 4] =
            make_float4(acc0[r][0] + bo, acc0[r][1] + bo, acc0[r][2] + bo, acc0[r][3] + bo);
        *(float4*)&op[64 + tx * 4] =
            make_float4(acc1[r][0] + bo, acc1[r][1] + bo, acc1[r][2] + bo, acc1[r][3] + bo);
    }
}

// ---------- K2: depthwise 3x3, pad 1, IN-PLACE; Cm channels also mirrored to cmws ----------
// v2: float4 global loads/stores, 4 outputs per thread with row-register reuse
__global__ __launch_bounds__(256) void k2_conv(float* __restrict__ buf,
                                               const float* __restrict__ wdw,
                                               const float* __restrict__ bdw,
                                               float* __restrict__ cmws) {
    int bc = blockIdx.x;          // b*192 + ch
    int b = bc / C3, ch = bc % C3;
    __shared__ float p[66 * 66];
    int t = threadIdx.x;
    // zero the halo border only
    for (int i = t; i < 66; i += 256) { p[i] = 0.f; p[65 * 66 + i] = 0.f; }
    for (int i = t; i < 64; i += 256) { p[(i + 1) * 66] = 0.f; p[(i + 1) * 66 + 65] = 0.f; }
    float* plane = buf + (size_t)bc * LL;
    const float4* plane4 = (const float4*)plane;
    for (int i = t; i < 1024; i += 256) {
        float4 v = plane4[i];
        int yy = i >> 4, xx = (i & 15) << 2;
        float* dst = &p[(yy + 1) * 66 + xx + 1];
        dst[0] = v.x; dst[1] = v.y; dst[2] = v.z; dst[3] = v.w;
    }
    __syncthreads();
    float wv[9];
#pragma unroll
    for (int k = 0; k < 9; ++k) wv[k] = wdw[ch * 9 + k];
    float bias = bdw[ch];
    bool is_cm = (ch >= 64 && ch < 128);
    float* cmp = is_cm ? (cmws + ((size_t)b * SD + (ch - 64)) * LL) : nullptr;
    for (int i = t; i < 1024; i += 256) {
        int yy = i >> 4, xx = (i & 15) << 2;
        float r0[6], r1[6], r2[6];
#pragma unroll
        for (int j = 0; j < 6; ++j) {
            r0[j] = p[(yy + 0) * 66 + xx + j];
            r1[j] = p[(yy + 1) * 66 + xx + j];
            r2[j] = p[(yy + 2) * 66 + xx + j];
        }
        float4 o;
        float* op = &o.x;
#pragma unroll
        for (int j = 0; j < 4; ++j) {
            op[j] = bias
                  + wv[0] * r0[j] + wv[1] * r0[j + 1] + wv[2] * r0[j + 2]
                  + wv[3] * r1[j] + wv[4] * r1[j + 1] + wv[5] * r1[j + 2]
                  + wv[6] * r2[j] + wv[7] * r2[j + 1] + wv[8] * r2[j + 2];
        }
        ((float4*)plane)[i] = o;
        if (is_cm) ((float4*)cmp)[i] = o;
    }
}

// ---------- K3: AB[b,s,l] = softmax_l(dt+A[s]) * Bm, written IN-PLACE over Bm channel ----------
__global__ __launch_bounds__(256) void k3_softmax(float* __restrict__ conv,
                                                  const float* __restrict__ Ap) {
    int bs = blockIdx.x;
    int b = bs >> 6, s = bs & 63;
    const float* dt = conv + ((size_t)b * C3 + 128 + s) * LL;   // dt = channels 128..191
    float* bm = conv + ((size_t)b * C3 + s) * LL;               // Bm = channels 0..63 (AB dest)
    float Av = Ap[s];
    int t = threadIdx.x;
    float v[16];
    float mx = -1e30f;
#pragma unroll
    for (int j = 0; j < 16; ++j) { v[j] = dt[j * 256 + t] + Av; mx = fmaxf(mx, v[j]); }
#pragma unroll
    for (int off = 32; off >= 1; off >>= 1) mx = fmaxf(mx, __shfl_xor(mx, off, 64));
    __shared__ float redm[4], reds[4];
    int wid = t >> 6, lane = t & 63;
    if (lane == 0) redm[wid] = mx;
    __syncthreads();
    mx = fmaxf(fmaxf(redm[0], redm[1]), fmaxf(redm[2], redm[3]));
    float sum = 0.f;
#pragma unroll
    for (int j = 0; j < 16; ++j) { v[j] = expf(v[j] - mx); sum += v[j]; }
#pragma unroll
    for (int off = 32; off >= 1; off >>= 1) sum += __shfl_xor(sum, off, 64);
    if (lane == 0) reds[wid] = sum;
    __syncthreads();
    sum = reds[0] + reds[1] + reds[2] + reds[3];
    float inv = 1.f / sum;
#pragma unroll
    for (int j = 0; j < 16; ++j) {
        float bmv = bm[j * 256 + t];            // read before overwrite (same thread/elem)
        bm[j * 256 + t] = v[j] * inv * bmv;
    }
}

// ---------- K4: hpart[p][b,c,s] = sum_{l in chunk p} x[b,c,l]*AB[b,s,l] ----------
// v2: split-K x8 for occupancy (1024 blocks), 128x64 tile, padded LDS, prefetch
constexpr int KP = 512;                       // K-chunk per partial
constexpr size_t HP_STRIDE = (size_t)BN * DM * SD;   // floats per partial
__global__ __launch_bounds__(256) void k4_h(const float* __restrict__ x,
                                            const float* __restrict__ conv,
                                            float* __restrict__ hpart) {
    int b = blockIdx.z, c0 = blockIdx.x * 128, part = blockIdx.y;
    int kbeg = part * KP;
    __shared__ float xl[16][132];   // [k][c] 128 rows + pad
    __shared__ float al[16][68];    // [k][s] + pad
    int t = threadIdx.x, tx = t & 15, ty = t >> 4;
    float acc0[4][4] = {}, acc1[4][4] = {};
    const float* xb = x + (size_t)b * DM * LL;
    const float* abb = conv + (size_t)b * C3 * LL;   // AB channels 0..63, stride LL
    int ri = t >> 2, kk4 = (t & 3) * 4;
    float4 xv0 = *(const float4*)&xb[(size_t)(c0 + ri) * LL + kbeg + kk4];
    float4 xv1 = *(const float4*)&xb[(size_t)(c0 + 64 + ri) * LL + kbeg + kk4];
    float4 av  = *(const float4*)&abb[(size_t)ri * LL + kbeg + kk4];
    for (int k0 = kbeg; k0 < kbeg + KP; k0 += 16) {
        xl[kk4 + 0][ri] = xv0.x; xl[kk4 + 1][ri] = xv0.y;
        xl[kk4 + 2][ri] = xv0.z; xl[kk4 + 3][ri] = xv0.w;
        xl[kk4 + 0][64 + ri] = xv1.x; xl[kk4 + 1][64 + ri] = xv1.y;
        xl[kk4 + 2][64 + ri] = xv1.z; xl[kk4 + 3][64 + ri] = xv1.w;
        al[kk4 + 0][ri] = av.x; al[kk4 + 1][ri] = av.y;
        al[kk4 + 2][ri] = av.z; al[kk4 + 3][ri] = av.w;
        __syncthreads();
        if (k0 + 16 < kbeg + KP) {
            xv0 = *(const float4*)&xb[(size_t)(c0 + ri) * LL + k0 + 16 + kk4];
            xv1 = *(const float4*)&xb[(size_t)(c0 + 64 + ri) * LL + k0 + 16 + kk4];
            av  = *(const float4*)&abb[(size_t)ri * LL + k0 + 16 + kk4];
        }
#pragma unroll
        for (int kk = 0; kk < 16; ++kk) {
            float4 a4 = *(const float4*)&xl[kk][ty * 4];
            float4 c4 = *(const float4*)&xl[kk][64 + ty * 4];
            float4 b4 = *(const float4*)&al[kk][tx * 4];
            OUTER16(acc0, a4, b4)
            OUTER16(acc1, c4, b4)
        }
        __syncthreads();
    }
    float* hp = hpart + (size_t)part * HP_STRIDE;
#pragma unroll
    for (int r = 0; r < 4; ++r) {
        *(float4*)&hp[((size_t)b * DM + c0 + ty * 4 + r) * SD + tx * 4] =
            make_float4(acc0[r][0], acc0[r][1], acc0[r][2], acc0[r][3]);
        *(float4*)&hp[((size_t)b * DM + c0 + 64 + ty * 4 + r) * SD + tx * 4] =
            make_float4(acc1[r][0], acc1[r][1], acc1[r][2], acc1[r][3]);
    }
}

// ---------- K4r: h = sum over 8 partials ----------
__global__ __launch_bounds__(256) void k4r(const float* __restrict__ hpart,
                                           float* __restrict__ h) {
    size_t i = (size_t)blockIdx.x * 256 + threadIdx.x;   // float4 index
    const float4* hp = (const float4*)hpart;
    constexpr size_t PS = HP_STRIDE / 4;                 // 262144 float4s
    float4 a = hp[i];
#pragma unroll
    for (int p = 1; p < 8; ++p) {
        float4 v = hp[i + (size_t)p * PS];
        a.x += v.x; a.y += v.y; a.z += v.z; a.w += v.w;
    }
    ((float4*)h)[i] = a;
}

// ---------- K5: fused hz-proj + silu-gate: hg[b,o,s] = h1*(silu(z)+D) ----------
__global__ __launch_bounds__(256) void k5_hz_gate(const float* __restrict__ w,
                                                  const float* __restrict__ bias,
                                                  const float* __restrict__ h,
                                                  const float* __restrict__ dskip,
                                                  float* __restrict__ hg) {
    int b = blockIdx.y, o0 = blockIdx.x * 64;
    __shared__ float wl1[16][64];   // [k][o] for h1 rows
    __shared__ float wl2[16][64];   // [k][o] for z rows
    __shared__ float hl[16][64];    // [k][s]
    int t = threadIdx.x, tx = t & 15, ty = t >> 4;
    float acc1[4][4] = {}, acc2[4][4] = {};
    const float* hb = h + (size_t)b * DM * SD;
    int oi = t >> 2, kkw = (t & 3) * 4;
    int kh = t >> 4, sh = (t & 15) * 4;
    for (int k0 = 0; k0 < DM; k0 += 16) {
        float4 w1 = *(const float4*)&w[(size_t)(o0 + oi) * DM + k0 + kkw];
        float4 w2 = *(const float4*)&w[(size_t)(o0 + 512 + oi) * DM + k0 + kkw];
        wl1[kkw + 0][oi] = w1.x; wl1[kkw + 1][oi] = w1.y;
        wl1[kkw + 2][oi] = w1.z; wl1[kkw + 3][oi] = w1.w;
        wl2[kkw + 0][oi] = w2.x; wl2[kkw + 1][oi] = w2.y;
        wl2[kkw + 2][oi] = w2.z; wl2[kkw + 3][oi] = w2.w;
        *(float4*)&hl[kh][sh] = *(const float4*)&hb[(size_t)(k0 + kh) * SD + sh];
        __syncthreads();
#pragma unroll
        for (int kk = 0; kk < 16; ++kk) {
            float4 b4 = *(const float4*)&hl[kk][tx * 4];
            float4 a4 = *(const float4*)&wl1[kk][ty * 4];
            OUTER16(acc1, a4, b4)
            float4 c4 = *(const float4*)&wl2[kk][ty * 4];
            OUTER16(acc2, c4, b4)
        }
        __syncthreads();
    }
    float d = dskip[0];
#pragma unroll
    for (int r = 0; r < 4; ++r) {
        int o = o0 + ty * 4 + r;
        float b1 = bias[o], b2 = bias[o + 512];
        float4 v;
        float* vp = &v.x;
#pragma unroll
        for (int j = 0; j < 4; ++j) {
            float h1 = acc1[r][j] + b1;
            float z  = acc2[r][j] + b2;
            float sig = 1.f / (1.f + expf(-z));
            vp[j] = h1 * (z * sig + d);
        }
        *(float4*)&hg[((size_t)b * DM + o) * SD + tx * 4] = v;
    }
}

// ---------- K5c: ho[b,o,s] = sum_c w_out[o,c]*hg[b,c,s] + b_out[o]  -> f32 ho in d_out ----------
__global__ __launch_bounds__(256) void k5c_out(const float* __restrict__ w,
                                               const float* __restrict__ bias,
                                               const float* __restrict__ hg,
                                               float* __restrict__ ho_out) {
    int b = blockIdx.y, o0 = blockIdx.x * 64;
    __shared__ float wl[16][64];   // [k][o]
    __shared__ float hl[16][64];   // [k][s]
    int t = threadIdx.x, tx = t & 15, ty = t >> 4;
    float acc[4][4] = {};
    const float* hb = hg + (size_t)b * DM * SD;
    int oi = t >> 2, kkw = (t & 3) * 4;
    int kh = t >> 4, sh = (t & 15) * 4;
    for (int k0 = 0; k0 < DM; k0 += 16) {
        float4 wv = *(const float4*)&w[(size_t)(o0 + oi) * DM + k0 + kkw];
        wl[kkw + 0][oi] = wv.x; wl[kkw + 1][oi] = wv.y;
        wl[kkw + 2][oi] = wv.z; wl[kkw + 3][oi] = wv.w;
        *(float4*)&hl[kh][sh] = *(const float4*)&hb[(size_t)(k0 + kh) * SD + sh];
        __syncthreads();
#pragma unroll
        for (int kk = 0; kk < 16; ++kk) {
            float4 a4 = *(const float4*)&wl[kk][ty * 4];
            float4 b4 = *(const float4*)&hl[kk][tx * 4];
            OUTER16(acc, a4, b4)
        }
        __syncthreads();
    }
#pragma unroll
    for (int r = 0; r < 4; ++r) {
        int o = o0 + ty * 4 + r;
        float bo = bias[o];
        float4 v = make_float4(acc[r][0] + bo, acc[r][1] + bo, acc[r][2] + bo, acc[r][3] + bo);
        *(float4*)&ho_out[((size_t)b * DM + o) * SD + tx * 4] = v;
    }
}

// ---------- K6: y[b,c,l] = sum_s ho[b,c,s]*Cm[b,s,l]  (Cm from ws copy; y overwrites conv) ----------
__global__ __launch_bounds__(256) void k6_y(const float* __restrict__ ho,
                                            const float* __restrict__ cmws,
                                            float* __restrict__ y) {
    int b = blockIdx.z, c0 = blockIdx.y * 64, l0 = blockIdx.x * 64;
    __shared__ float hl[16][64];   // [k][c]
    __shared__ float cl[16][64];   // [k][l]
    int t = threadIdx.x, tx = t & 15, ty = t >> 4;
    float acc[4][4] = {};
    const float* hb = ho + (size_t)b * DM * SD;
    const float* cm = cmws + (size_t)b * SD * LL;
    int ci = t >> 2, kkh = (t & 3) * 4;
    int kc = t >> 4, li = (t & 15) * 4;
    for (int k0 = 0; k0 < SD; k0 += 16) {
        float4 hv = *(const float4*)&hb[(size_t)(c0 + ci) * SD + k0 + kkh];
        hl[kkh + 0][ci] = hv.x; hl[kkh + 1][ci] = hv.y;
        hl[kkh + 2][ci] = hv.z; hl[kkh + 3][ci] = hv.w;
        *(float4*)&cl[kc][li] = *(const float4*)&cm[(size_t)(k0 + kc) * LL + l0 + li];
        __syncthreads();
#pragma unroll
        for (int kk = 0; kk < 16; ++kk) {
            float4 a4 = *(const float4*)&hl[kk][ty * 4];
            float4 b4 = *(const float4*)&cl[kk][tx * 4];
            OUTER16(acc, a4, b4)
        }
        __syncthreads();
    }
#pragma unroll
    for (int r = 0; r < 4; ++r)
        *(float4*)&y[((size_t)b * DM + c0 + ty * 4 + r) * LL + l0 + tx * 4] =
            make_float4(acc[r][0], acc[r][1], acc[r][2], acc[r][3]);
}

extern "C" void kernel_launch(void* const* d_in, const int* in_sizes, int n_in,
                              void* d_out, int out_size, void* d_ws, size_t ws_size,
                              hipStream_t stream) {
    const float* x      = (const float*)d_in[0];
    const float* w_bcdt = (const float*)d_in[1];
    const float* b_bcdt = (const float*)d_in[2];
    const float* w_dw   = (const float*)d_in[3];
    const float* b_dw   = (const float*)d_in[4];
    const float* w_hz   = (const float*)d_in[5];
    const float* b_hz   = (const float*)d_in[6];
    const float* w_out  = (const float*)d_in[7];
    const float* b_out  = (const float*)d_in[8];
    const float* A      = (const float*)d_in[9];
    const float* Dskip  = (const float*)d_in[10];

    float* y_out  = (float*)d_out;                      // [32,512,4096] f32 (268.4 MB)
    float* ho_out = y_out + (size_t)BN * DM * LL;       // [32,512,64]   f32 (4.2 MB)

    // conv [32,192,4096] f32 = 100.7 MB staged INSIDE the y region of d_out
    // (fully consumed by K3/K4 before K6 overwrites the region with y).
    float* conv = y_out;

    // hpart [8][32,512,64] f32 = 33.6 MB staged in d_out at +128 MiB
    // (past conv's 96 MiB, consumed by k4r before K6 writes y).
    float* hpart = y_out + (size_t)33554432;

    // ws: Cm copy (33.5 MB) + h (4.2 MB) + hg (4.2 MB) = 41.9 MB
    char* ws = (char*)d_ws;
    float* cmws = (float*)(ws + 0);           // [32,64,4096] f32
    float* h    = (float*)(ws + 33554432);    // [32,512,64]  f32
    float* hg   = (float*)(ws + 37748736);    // [32,512,64]  f32

    k1_bcdt<<<dim3(32, 3, 32), 256, 0, stream>>>(x, w_bcdt, b_bcdt, conv);
    k2_conv<<<dim3(BN * C3), 256, 0, stream>>>(conv, w_dw, b_dw, cmws);
    k3_softmax<<<dim3(BN * SD), 256, 0, stream>>>(conv, A);
    k4_h<<<dim3(4, 8, BN), 256, 0, stream>>>(x, conv, hpart);
    k4r<<<dim3(1024), 256, 0, stream>>>(hpart, h);
    k5_hz_gate<<<dim3(8, BN), 256, 0, stream>>>(w_hz, b_hz, h, Dskip, hg);
    k5c_out<<<dim3(8, BN), 256, 0, stream>>>(w_out, b_out, hg, ho_out);
    k6_y<<<dim3(64, 8, BN), 256, 0, stream>>>(ho_out, cmws, y_out);
}